// Round 13
// baseline (319.537 us; speedup 1.0000x reference)
//
#include <hip/hip_runtime.h>
#include <cstdint>

typedef _Float16 h2 __attribute__((ext_vector_type(2)));
typedef _Float16 h4 __attribute__((ext_vector_type(4)));
typedef _Float16 h8 __attribute__((ext_vector_type(8)));
typedef float f32x4 __attribute__((ext_vector_type(4)));
typedef float f32x16 __attribute__((ext_vector_type(16)));

__device__ __forceinline__ h2 cvt_pk(float a, float b) {
  return __builtin_bit_cast(h2, __builtin_amdgcn_cvt_pkrtz(a, b));
}

// single-instruction 2^x (exp2f without fast-math lowers to a multi-op ocml
// sequence; our args are bounded so the bare HW instruction is exact enough)
__device__ __forceinline__ float exp2_raw(float x) {
  float r;
  asm("v_exp_f32 %0, %1" : "=v"(r) : "v"(x));
  return r;
}

// ---------- async global->LDS, 16B per lane, wave-uniform LDS base ----------
__device__ __forceinline__ void g2l16(const void* g, void* l) {
  __builtin_amdgcn_global_load_lds(
      (__attribute__((address_space(1))) void*)(uintptr_t)(g),
      (__attribute__((address_space(3))) void*)(l), 16, 0, 0);
}

// ---------------- fp32 -> fp16 elementwise ----------------
__global__ __launch_bounds__(256) void convk(const float* __restrict__ in,
                                             _Float16* __restrict__ out, int n) {
  int i = (blockIdx.x * 256 + threadIdx.x) * 4;
  if (i + 3 < n) {
    const float4 v = *(const float4*)(in + i);
    h4 o;
    o[0] = (_Float16)v.x; o[1] = (_Float16)v.y; o[2] = (_Float16)v.z; o[3] = (_Float16)v.w;
    *(h4*)(out + i) = o;
  }
}

// ---------------- fp32 [R][C] -> fp16 [C][R] transpose-convert ----------------
__global__ __launch_bounds__(256) void transconv_k(const float* __restrict__ in,
                                                   _Float16* __restrict__ out,
                                                   int R, int C) {
  __shared__ float tile[64][65];
  const int tC = C >> 6;
  const int bc = blockIdx.x % tC, br = blockIdx.x / tC;
  const int r0 = br << 6, c0 = bc << 6;
  const int t = threadIdx.x;
  const int lr = t >> 4, lc = (t & 15) << 2;
#pragma unroll
  for (int p = 0; p < 4; ++p) {
    const float4 v = *(const float4*)(in + (size_t)(r0 + p * 16 + lr) * C + c0 + lc);
    tile[p * 16 + lr][lc + 0] = v.x;
    tile[p * 16 + lr][lc + 1] = v.y;
    tile[p * 16 + lr][lc + 2] = v.z;
    tile[p * 16 + lr][lc + 3] = v.w;
  }
  __syncthreads();
#pragma unroll
  for (int p = 0; p < 4; ++p) {
    const int oc = p * 16 + lr;  // out-row = in-col
    h4 v;
#pragma unroll
    for (int e = 0; e < 4; ++e) v[e] = (_Float16)tile[lc + e][oc];
    *(h4*)(out + (size_t)(c0 + oc) * R + r0 + lc) = v;
  }
}

// ---- staging: 256rx32c A (4 chunks/thread) + 128rx32c B (2 chunks/thread) ----
// LDS layout: row-major [row][32 fp16] (64B rows), XOR-swizzled: phys = log ^ ((row&6)<<3).
// global_load_lds writes LINEAR (wave-uniform dest + lane*16B); we pre-swizzle the
// per-lane GLOBAL source so linear LDS holds the swizzled layout (both-sides rule).
__device__ __forceinline__ void stage_chunk(const _Float16* X, int R0, int K, int kof,
                                            _Float16* ldsbase, int chunk, int lane) {
  const int b = chunk * 1024 + lane * 16;           // linear LDS byte offset
  const int l = b ^ (((b >> 6) & 6) << 3);          // logical byte (involution)
  const _Float16* src = X + (size_t)(R0 + (l >> 6)) * K + kof + ((l & 63) >> 1);
  g2l16(src, (char*)ldsbase + chunk * 1024);
}

// ---------------- GEMM: C[M][N] = A[M][K] * BT[N][K]^T  (fp16 in, fp32 acc) ----------------
// BM=256 BN=128 BK=32, 256 threads (4 waves = 2wr x 2wc), per-wave 128x64 = acc[8][4].
// Per-wave ratio: 32 MFMA (128 cyc) : 12 ds_read_b128 (144 cyc) -> MfmaUtil ceiling ~89%
// (previous 64x64/wave: 64:96 cyc -> 67% ceiling; measured 38.7%).
// Deep pipeline (T3/T4): 2-deep prefetch, counted s_waitcnt vmcnt(6) (never 0 in
// steady state), raw s_barrier, stage(t+2) after consume-barrier. T2 bank swizzle
// (measured conflict-free). T5 setprio.
// MODE 0: plain fp32 store to fo (N = NTILES*128)
// MODE 1: QKV epilogue: l2norm + rope; q/k/v written in attn FRAGMENT ORDER:
//   [bh][blk32][frag:4][lane:64][8 fp16]. Q additionally scaled by 0.125*log2(e).
template <int MODE>
__global__ __launch_bounds__(256) void gemm_k(
    const _Float16* __restrict__ A, const _Float16* __restrict__ BT,
    const int K, const int NTILES,
    _Float16* __restrict__ outq, _Float16* __restrict__ outk,
    _Float16* __restrict__ outv, const float* __restrict__ freqs,
    float* __restrict__ fo) {
  __shared__ __align__(16) _Float16 Ls[2][12288];  // [dbuf][A:16KB | B:8KB] = 48KB
  const int tid = threadIdx.x;
  // XCD-chunked + 4bt x 2mb grouped ordering (gridDim.x % 8 == 0, MBC = cpx/NTILES)
  const int cpx = gridDim.x >> 3;
  const int xcd = blockIdx.x & 7, idx = blockIdx.x >> 3;
  const int MBC = cpx / NTILES;
  const int grp = idx >> 3, sub = idx & 7;
  const int bt = grp * 4 + (sub & 3);
  const int mb = xcd * MBC + (sub >> 2);
  const int m0 = mb * 256, n0 = bt * 128;
  const int wid = tid >> 6, lane = tid & 63;
  const int wr = wid >> 1, wc = wid & 1;  // 2 x 2 waves; per-wave 128 rows x 64 cols
  const int g = lane >> 4, c = lane & 15;

  f32x4 acc[8][4];
#pragma unroll
  for (int i = 0; i < 8; ++i)
#pragma unroll
    for (int j = 0; j < 4; ++j)
#pragma unroll
      for (int e = 0; e < 4; ++e) acc[i][j][e] = 0.f;

  const int sx = (c & 6) << 3;
  const int nk = K >> 5;

  // prologue: stage tiles 0,1 (6 g2l16/thread each: A chunks p*4+wid p=0..3, B p=0..1)
#pragma unroll
  for (int t0 = 0; t0 < 2; ++t0) {
#pragma unroll
    for (int p = 0; p < 4; ++p) stage_chunk(A, m0, K, t0 * 32, Ls[t0], p * 4 + wid, lane);
#pragma unroll
    for (int p = 0; p < 2; ++p)
      stage_chunk(BT, n0, K, t0 * 32, Ls[t0] + 8192, p * 4 + wid, lane);
  }

  for (int kt = 0; kt < nk; ++kt) {
    if (kt < nk - 1) {
      asm volatile("s_waitcnt vmcnt(6)" ::: "memory");  // own stage(kt) done; kt+1 in flight
    } else {
      asm volatile("s_waitcnt vmcnt(0)" ::: "memory");  // last tile: drain
    }
    __builtin_amdgcn_s_barrier();  // all waves' stage(kt) complete -> buf ready
    const int db = kt & 1;
    const _Float16* Ab = Ls[db];
    const _Float16* Bb = Ls[db] + 8192;
    h8 af[8], bf[4];
#pragma unroll
    for (int t = 0; t < 8; ++t) {
      const int lg = (wr * 128 + t * 16 + c) * 64 + 16 * g;
      af[t] = *(const h8*)((const char*)Ab + (lg ^ sx));
    }
#pragma unroll
    for (int t = 0; t < 4; ++t) {
      const int lg = (wc * 64 + t * 16 + c) * 64 + 16 * g;
      bf[t] = *(const h8*)((const char*)Bb + (lg ^ sx));
    }
    __builtin_amdgcn_s_setprio(1);
#pragma unroll
    for (int i = 0; i < 8; ++i)
#pragma unroll
      for (int j = 0; j < 4; ++j)
        acc[i][j] = __builtin_amdgcn_mfma_f32_16x16x32_f16(af[i], bf[j], acc[i][j], 0, 0, 0);
    __builtin_amdgcn_s_setprio(0);
    __builtin_amdgcn_s_barrier();  // all waves consumed buf[db]
    const int nx = kt + 2;
    if (nx < nk) {  // overwrite buf[db]; overlaps compute of kt+1
#pragma unroll
      for (int p = 0; p < 4; ++p) stage_chunk(A, m0, K, nx * 32, Ls[db], p * 4 + wid, lane);
#pragma unroll
      for (int p = 0; p < 2; ++p)
        stage_chunk(BT, n0, K, nx * 32, Ls[db] + 8192, p * 4 + wid, lane);
    }
  }

  if (MODE == 0) {
    const int Ncols = NTILES * 128;
#pragma unroll
    for (int mt = 0; mt < 8; ++mt)
#pragma unroll
      for (int i = 0; i < 4; ++i) {
        const int m = m0 + wr * 128 + mt * 16 + 4 * g + i;
        float* orow = fo + (size_t)m * Ncols + n0 + wc * 64 + c;
#pragma unroll
        for (int nt = 0; nt < 4; ++nt) orow[nt * 16] = acc[mt][nt][i];
      }
  } else {
    const int hh = ((bt & 15) << 1) | wc;  // head 0..31 within its third
    const int third = bt >> 4;             // 0=q 1=k 2=v
    if (third < 2) {
      _Float16* dst0 = (third == 0) ? outq : outk;
#pragma unroll
      for (int mt = 0; mt < 8; ++mt) {
        float ss[4];
#pragma unroll
        for (int i = 0; i < 4; ++i) {
          float s = 0.f;
#pragma unroll
          for (int nt = 0; nt < 4; ++nt) { const float v = acc[mt][nt][i]; s += v * v; }
          ss[i] = s;
        }
#pragma unroll
        for (int msk = 1; msk < 16; msk <<= 1)
#pragma unroll
          for (int i = 0; i < 4; ++i) ss[i] += __shfl_xor(ss[i], msk);
#pragma unroll
        for (int i = 0; i < 4; ++i) {
          const int m = m0 + wr * 128 + mt * 16 + 4 * g + i;
          const int b = m >> 11, pos = m & 2047;
          float inv = 1.0f / fmaxf(sqrtf(ss[i]), 1e-12f);
          if (third == 0) inv *= 0.1803368801f;  // 0.125 * log2(e) folded into q
          const float v0 = acc[mt][0][i] * inv, v1 = acc[mt][1][i] * inv;
          const float v2 = acc[mt][2][i] * inv, v3 = acc[mt][3][i] * inv;
          float sn, cs;
          __sincosf(freqs[pos * 32 + c], &sn, &cs);
          // fragment-order store: blk=pos>>5, frag=nt, lane=(c>>3)*32+(pos&31), elem=c&7
          _Float16* d = dst0 + ((size_t)((b << 5) | hh) * 64 + (pos >> 5)) * 2048 +
                        ((c >> 3) * 32 + (pos & 31)) * 8 + (c & 7);
          d[0]    = (_Float16)(v0 * cs - v1 * sn);
          d[512]  = (_Float16)(v1 * cs + v0 * sn);
          d[1024] = (_Float16)v2;
          d[1536] = (_Float16)v3;
        }
      }
    } else {
#pragma unroll
      for (int mt = 0; mt < 8; ++mt)
#pragma unroll
        for (int i = 0; i < 4; ++i) {
          const int m = m0 + wr * 128 + mt * 16 + 4 * g + i;
          const int b = m >> 11, pos = m & 2047;
          const int kvb = pos >> 5, sub2 = (pos >> 4) & 1, rem = pos & 15;
          const int vhi = (rem >> 2) & 1;
          const int vj = (rem & 3) + ((rem >> 3) << 2);
          const size_t hbase = ((size_t)((b << 5) | hh) * 64 + kvb) * 2048;
#pragma unroll
          for (int nt = 0; nt < 4; ++nt) {
            const int dta = nt >> 1;
            const int lfrag = vhi * 32 + (nt & 1) * 16 + c;
            outv[hbase + ((dta * 2 + sub2) * 64 + lfrag) * 8 + vj] = (_Float16)acc[mt][nt][i];
          }
        }
    }
  }
}

// ---------------- flash attention, swapped QK^T, fragment-order inputs ----------------
// 1 wave = 32 q rows (1 q-block), half the kv range; grid 2048 = 8 blocks/CU backlog.
// All loads base + lane*16B (coalesced, direct L2). Q pre-scaled by 0.125*log2e.
// exp via bare v_exp_f32 (exp2f lowers to a multi-op sequence without fast-math).
__global__ __launch_bounds__(256) void attn_k(const _Float16* __restrict__ qf_,
                                              const _Float16* __restrict__ kf_,
                                              const _Float16* __restrict__ vf_,
                                              _Float16* __restrict__ pO,
                                              float* __restrict__ lsums) {
  const int tid = threadIdx.x;
  const int wid = tid >> 6;
  const int lane = tid & 63;
  const int l31 = tid & 31;
  const int hi = (tid >> 5) & 1;
  // XCD swizzle: 16 consecutive blocks (one (bh,s)) per XCD for K/V L2 residency
  const int dd = blockIdx.x;
  const int xcd = dd & 7, j = dd >> 3;
  const int id = xcd * 16 + (j >> 4);  // (bh,split) id in [0,128)
  const int bh = id >> 1, s = id & 1;
  const int qg = j & 15;
  const int qb = (qg << 2) | wid;      // q-block 0..63
  const int q = qb * 32 + l31;

  const _Float16* qp = qf_ + ((size_t)bh * 64 + qb) * 2048 + lane * 8;
  h8 qfr[4];
#pragma unroll
  for (int dc = 0; dc < 4; ++dc) qfr[dc] = *(const h8*)(qp + dc * 512);

  const _Float16* kp = kf_ + ((size_t)bh * 64 + s * 32) * 2048 + lane * 8;
  const _Float16* vp = vf_ + ((size_t)bh * 64 + s * 32) * 2048 + lane * 8;

  f32x16 acc0, acc1;
#pragma unroll
  for (int e = 0; e < 16; ++e) { acc0[e] = 0.f; acc1[e] = 0.f; }
  float l0 = 0.f, l1 = 0.f, l2 = 0.f, l3 = 0.f;  // 4 independent lsum chains

  for (int it = 0; it < 32; ++it) {
    const _Float16* kb = kp + (size_t)it * 2048;
    const _Float16* vb = vp + (size_t)it * 2048;
    // all 8 loads issued up front (independent of QK/exp)
    h8 kf0 = *(const h8*)(kb);
    h8 kf1 = *(const h8*)(kb + 512);
    h8 kf2 = *(const h8*)(kb + 1024);
    h8 kf3 = *(const h8*)(kb + 1536);
    h8 v00 = *(const h8*)(vb);          // dta0 sub0
    h8 v01 = *(const h8*)(vb + 512);    // dta0 sub1
    h8 v10 = *(const h8*)(vb + 1024);   // dta1 sub0
    h8 v11 = *(const h8*)(vb + 1536);   // dta1 sub1

    f32x16 S;
#pragma unroll
    for (int e = 0; e < 16; ++e) S[e] = 0.f;
    __builtin_amdgcn_s_setprio(1);
    S = __builtin_amdgcn_mfma_f32_32x32x16_f16(kf0, qfr[0], S, 0, 0, 0);
    S = __builtin_amdgcn_mfma_f32_32x32x16_f16(kf1, qfr[1], S, 0, 0, 0);
    S = __builtin_amdgcn_mfma_f32_32x32x16_f16(kf2, qfr[2], S, 0, 0, 0);
    S = __builtin_amdgcn_mfma_f32_32x32x16_f16(kf3, qfr[3], S, 0, 0, 0);
    __builtin_amdgcn_s_setprio(0);

    // p = exp2(S) via single v_exp_f32 (scale pre-folded into q; |arg| bounded).
    float p[16];
#pragma unroll
    for (int e = 0; e < 16; ++e) p[e] = exp2_raw(S[e]);
    l0 += p[0]; l1 += p[1]; l2 += p[2]; l3 += p[3];
    l0 += p[4]; l1 += p[5]; l2 += p[6]; l3 += p[7];
    l0 += p[8]; l1 += p[9]; l2 += p[10]; l3 += p[11];
    l0 += p[12]; l1 += p[13]; l2 += p[14]; l3 += p[15];

    // packed fp16 conversion (RTZ): pb0 = p[0..7], pb1 = p[8..15]
    h2 c0 = cvt_pk(p[0], p[1]);
    h2 c1 = cvt_pk(p[2], p[3]);
    h2 c2 = cvt_pk(p[4], p[5]);
    h2 c3 = cvt_pk(p[6], p[7]);
    h2 c4 = cvt_pk(p[8], p[9]);
    h2 c5 = cvt_pk(p[10], p[11]);
    h2 c6 = cvt_pk(p[12], p[13]);
    h2 c7 = cvt_pk(p[14], p[15]);
    h4 x0 = __builtin_shufflevector(c0, c1, 0, 1, 2, 3);
    h4 x1 = __builtin_shufflevector(c2, c3, 0, 1, 2, 3);
    h4 x2 = __builtin_shufflevector(c4, c5, 0, 1, 2, 3);
    h4 x3 = __builtin_shufflevector(c6, c7, 0, 1, 2, 3);
    h8 pb0 = __builtin_shufflevector(x0, x1, 0, 1, 2, 3, 4, 5, 6, 7);
    h8 pb1 = __builtin_shufflevector(x2, x3, 0, 1, 2, 3, 4, 5, 6, 7);

    __builtin_amdgcn_s_setprio(1);
    acc0 = __builtin_amdgcn_mfma_f32_32x32x16_f16(v00, pb0, acc0, 0, 0, 0);
    acc0 = __builtin_amdgcn_mfma_f32_32x32x16_f16(v01, pb1, acc0, 0, 0, 0);
    acc1 = __builtin_amdgcn_mfma_f32_32x32x16_f16(v10, pb0, acc1, 0, 0, 0);
    acc1 = __builtin_amdgcn_mfma_f32_32x32x16_f16(v11, pb1, acc1, 0, 0, 0);
    __builtin_amdgcn_s_setprio(0);
  }

  float lsum = (l0 + l1) + (l2 + l3);
  lsum += __shfl_xor(lsum, 32);
  if (!hi) lsums[(size_t)s * 131072 + (size_t)bh * 2048 + q] = lsum;

  _Float16* orow = pO + (size_t)s * 8388608 + ((size_t)bh * 2048 + q) * 64;
#pragma unroll
  for (int dta = 0; dta < 2; ++dta) {
#pragma unroll
    for (int blk = 0; blk < 4; ++blk) {
      h4 st;
#pragma unroll
      for (int e = 0; e < 4; ++e) {
        const float v = (dta == 0) ? acc0[blk * 4 + e] : acc1[blk * 4 + e];
        st[e] = (_Float16)v;
      }
      *(h4*)(orow + dta * 32 + blk * 8 + 4 * hi) = st;
    }
  }
}

// ---------------- combine partials: attno[b][q][h*64+d] = (p0+p1)/(l0+l1) ----------------
__global__ __launch_bounds__(256) void combine_k(const _Float16* __restrict__ pO,
                                                 const float* __restrict__ lsums,
                                                 _Float16* __restrict__ attno) {
  const int idx = blockIdx.x * 256 + threadIdx.x;
  const int row = idx >> 3;           // bh*2048 + q, in [0, 131072)
  const int dpart = (idx & 7) * 8;
  const int bh = row >> 11, q = row & 2047;
  const float inv = 1.0f / (lsums[row] + lsums[131072 + row]);
  const h8 a = *(const h8*)(pO + (size_t)row * 64 + dpart);
  const h8 b = *(const h8*)(pO + 8388608 + (size_t)row * 64 + dpart);
  h8 o;
#pragma unroll
  for (int e = 0; e < 8; ++e) o[e] = (_Float16)(((float)a[e] + (float)b[e]) * inv);
  const int bb = bh >> 5, h = bh & 31;
  *(h8*)(attno + ((size_t)bb * 2048 + q) * 2048 + h * 64 + dpart) = o;
}

extern "C" void kernel_launch(void* const* d_in, const int* in_sizes, int n_in,
                              void* d_out, int out_size, void* d_ws, size_t ws_size,
                              hipStream_t stream) {
  const float* x = (const float*)d_in[0];
  const float* wqkv = (const float*)d_in[1];
  const float* wout = (const float*)d_in[2];
  const float* freqs = (const float*)d_in[3];
  char* ws = (char*)d_ws;
  _Float16* xb    = (_Float16*)ws;                          // [0,16M)  gemm1 A input
  _Float16* pO    = xb;                                     // [0,32M)  attn partials (x/wqkvT dead)
  _Float16* wqkvT = (_Float16*)(ws + (size_t)(16 << 20));   // [16,40M) gemm1 B input
  float*    lsums = (float*)(ws + (size_t)(32 << 20));      // [32,33M) partial lsums (wqkvT dead)
  _Float16* woutT = (_Float16*)(ws + (size_t)(40 << 20));   // [40,48M)
  _Float16* qn    = (_Float16*)(ws + (size_t)(48 << 20));   // [48,64M) q-frags; attno after attn
  _Float16* attno = qn;                                     //          (q dead after attn)
  _Float16* kn    = (_Float16*)(ws + (size_t)(64 << 20));   // [64,80M) k-frags
  _Float16* vT    = (_Float16*)(ws + (size_t)(80 << 20));   // [80,96M) v-frags
  float* out = (float*)d_out;

  convk<<<8192, 256, 0, stream>>>(x, xb, 2 * 2048 * 2048);
  transconv_k<<<(6144 / 64) * (2048 / 64), 256, 0, stream>>>(wqkv, wqkvT, 2048, 6144);
  transconv_k<<<(2048 / 64) * (2048 / 64), 256, 0, stream>>>(wout, woutT, 2048, 2048);
  // BM=256 BN=128, 256 threads (4 waves, 128x64/wave): grid = (M/256) * (N/128)
  gemm_k<1><<<16 * 48, 256, 0, stream>>>(xb, wqkvT, 2048, 48, qn, kn, vT, freqs, nullptr);
  attn_k<<<2048, 256, 0, stream>>>(qn, kn, vT, pO, lsums);
  combine_k<<<4096, 256, 0, stream>>>(pO, lsums, attno);
  gemm_k<0><<<16 * 16, 256, 0, stream>>>(attno, woutT, 2048, 16, nullptr, nullptr, nullptr,
                                         nullptr, out);
}

// Round 14
// 295.699 us; speedup vs baseline: 1.0806x; 1.0806x over previous
//
#include <hip/hip_runtime.h>
#include <cstdint>

typedef _Float16 h2 __attribute__((ext_vector_type(2)));
typedef _Float16 h4 __attribute__((ext_vector_type(4)));
typedef _Float16 h8 __attribute__((ext_vector_type(8)));
typedef float f32x4 __attribute__((ext_vector_type(4)));
typedef float f32x16 __attribute__((ext_vector_type(16)));

__device__ __forceinline__ h2 cvt_pk(float a, float b) {
  return __builtin_bit_cast(h2, __builtin_amdgcn_cvt_pkrtz(a, b));
}

// single-instruction 2^x (exp2f without fast-math lowers to a multi-op ocml
// sequence; our args are bounded so the bare HW instruction is exact enough)
__device__ __forceinline__ float exp2_raw(float x) {
  float r;
  asm("v_exp_f32 %0, %1" : "=v"(r) : "v"(x));
  return r;
}

// ---------- async global->LDS, 16B per lane, wave-uniform LDS base ----------
__device__ __forceinline__ void g2l16(const void* g, void* l) {
  __builtin_amdgcn_global_load_lds(
      (__attribute__((address_space(1))) void*)(uintptr_t)(g),
      (__attribute__((address_space(3))) void*)(l), 16, 0, 0);
}

// ---------------- fp32 -> fp16 elementwise ----------------
__global__ __launch_bounds__(256) void convk(const float* __restrict__ in,
                                             _Float16* __restrict__ out, int n) {
  int i = (blockIdx.x * 256 + threadIdx.x) * 4;
  if (i + 3 < n) {
    const float4 v = *(const float4*)(in + i);
    h4 o;
    o[0] = (_Float16)v.x; o[1] = (_Float16)v.y; o[2] = (_Float16)v.z; o[3] = (_Float16)v.w;
    *(h4*)(out + i) = o;
  }
}

// ---------------- fp32 [R][C] -> fp16 [C][R] transpose-convert ----------------
__global__ __launch_bounds__(256) void transconv_k(const float* __restrict__ in,
                                                   _Float16* __restrict__ out,
                                                   int R, int C) {
  __shared__ float tile[64][65];
  const int tC = C >> 6;
  const int bc = blockIdx.x % tC, br = blockIdx.x / tC;
  const int r0 = br << 6, c0 = bc << 6;
  const int t = threadIdx.x;
  const int lr = t >> 4, lc = (t & 15) << 2;
#pragma unroll
  for (int p = 0; p < 4; ++p) {
    const float4 v = *(const float4*)(in + (size_t)(r0 + p * 16 + lr) * C + c0 + lc);
    tile[p * 16 + lr][lc + 0] = v.x;
    tile[p * 16 + lr][lc + 1] = v.y;
    tile[p * 16 + lr][lc + 2] = v.z;
    tile[p * 16 + lr][lc + 3] = v.w;
  }
  __syncthreads();
#pragma unroll
  for (int p = 0; p < 4; ++p) {
    const int oc = p * 16 + lr;  // out-row = in-col
    h4 v;
#pragma unroll
    for (int e = 0; e < 4; ++e) v[e] = (_Float16)tile[lc + e][oc];
    *(h4*)(out + (size_t)(c0 + oc) * R + r0 + lc) = v;
  }
}

// ---- staging: one 256rx32c (A, 2 chunks/thread) or 128rx32c (B, 1 chunk) tile ----
// LDS layout: row-major [row][32 fp16] (64B rows), XOR-swizzled: phys = log ^ ((row&6)<<3).
// global_load_lds writes LINEAR (wave-uniform dest + lane*16B); we pre-swizzle the
// per-lane GLOBAL source so linear LDS holds the swizzled layout (both-sides rule).
__device__ __forceinline__ void stage_chunk(const _Float16* X, int R0, int K, int kof,
                                            _Float16* ldsbase, int chunk, int lane) {
  const int b = chunk * 1024 + lane * 16;           // linear LDS byte offset
  const int l = b ^ (((b >> 6) & 6) << 3);          // logical byte (involution)
  const _Float16* src = X + (size_t)(R0 + (l >> 6)) * K + kof + ((l & 63) >> 1);
  g2l16(src, (char*)ldsbase + chunk * 1024);
}

// ---------------- GEMM: C[M][N] = A[M][K] * BT[N][K]^T  (fp16 in, fp32 acc) ----------------
// R12-measured best: BM=256 BN=128 BK=32, 512 threads (8 waves = 4wr x 2wc, 64x64/wave).
// Deep pipeline (T3/T4): 2-deep prefetch, counted s_waitcnt vmcnt(3), raw s_barrier,
// stage(t+2) after consume-barrier. T2 bank swizzle. T5 setprio.
// (Measured: 124 us gemm1, MfmaUtil 38.7%, VGPR 60, bank-conflict 0.)
// MODE 0: plain fp32 store to fo (N = NTILES*128)
// MODE 1: QKV epilogue: l2norm + rope; q/k/v written in attn FRAGMENT ORDER:
//   [bh][blk32][frag:4][lane:64][8 fp16]. Q additionally scaled by 0.125*log2(e).
template <int MODE>
__global__ __launch_bounds__(512) void gemm_k(
    const _Float16* __restrict__ A, const _Float16* __restrict__ BT,
    const int K, const int NTILES,
    _Float16* __restrict__ outq, _Float16* __restrict__ outk,
    _Float16* __restrict__ outv, const float* __restrict__ freqs,
    float* __restrict__ fo) {
  __shared__ __align__(16) _Float16 Ls[2][12288];  // [dbuf][A:8192 | B:4096] = 48KB
  const int tid = threadIdx.x;
  // XCD-chunked + 4bt x 2mb grouped ordering (gridDim.x % 8 == 0, MBC = cpx/NTILES)
  const int cpx = gridDim.x >> 3;
  const int xcd = blockIdx.x & 7, idx = blockIdx.x >> 3;
  const int MBC = cpx / NTILES;
  const int grp = idx >> 3, sub = idx & 7;
  const int bt = grp * 4 + (sub & 3);
  const int mb = xcd * MBC + (sub >> 2);
  const int m0 = mb * 256, n0 = bt * 128;
  const int wid = tid >> 6, lane = tid & 63;
  const int wr = wid >> 1, wc = wid & 1;  // 4 x 2 waves
  const int g = lane >> 4, c = lane & 15;

  f32x4 acc[4][4];
#pragma unroll
  for (int i = 0; i < 4; ++i)
#pragma unroll
    for (int j = 0; j < 4; ++j)
#pragma unroll
      for (int e = 0; e < 4; ++e) acc[i][j][e] = 0.f;

  const int sx = (c & 6) << 3;
  const int nk = K >> 5;

  // prologue: stage tiles 0,1 (3 g2l16/thread each; 6 outstanding)
#pragma unroll
  for (int t0 = 0; t0 < 2; ++t0) {
    stage_chunk(A, m0, K, t0 * 32, Ls[t0], (0 * 8 + wid), lane);
    stage_chunk(A, m0, K, t0 * 32, Ls[t0], (1 * 8 + wid), lane);
    stage_chunk(BT, n0, K, t0 * 32, Ls[t0] + 8192, wid, lane);
  }

  for (int kt = 0; kt < nk; ++kt) {
    if (kt < nk - 1) {
      asm volatile("s_waitcnt vmcnt(3)" ::: "memory");  // own stage(kt) done; kt+1 in flight
    } else {
      asm volatile("s_waitcnt vmcnt(0)" ::: "memory");  // last tile: drain
    }
    __builtin_amdgcn_s_barrier();  // all waves' stage(kt) complete -> buf ready
    const int db = kt & 1;
    const _Float16* Ab = Ls[db];
    const _Float16* Bb = Ls[db] + 8192;
    h8 af[4], bf[4];
#pragma unroll
    for (int t = 0; t < 4; ++t) {
      const int lg = (wr * 64 + t * 16 + c) * 64 + 16 * g;
      af[t] = *(const h8*)((const char*)Ab + (lg ^ sx));
    }
#pragma unroll
    for (int t = 0; t < 4; ++t) {
      const int lg = (wc * 64 + t * 16 + c) * 64 + 16 * g;
      bf[t] = *(const h8*)((const char*)Bb + (lg ^ sx));
    }
    __builtin_amdgcn_s_setprio(1);
#pragma unroll
    for (int i = 0; i < 4; ++i)
#pragma unroll
      for (int j = 0; j < 4; ++j)
        acc[i][j] = __builtin_amdgcn_mfma_f32_16x16x32_f16(af[i], bf[j], acc[i][j], 0, 0, 0);
    __builtin_amdgcn_s_setprio(0);
    __builtin_amdgcn_s_barrier();  // all waves consumed buf[db]
    const int nx = kt + 2;
    if (nx < nk) {  // overwrite buf[db]; overlaps compute of kt+1
      stage_chunk(A, m0, K, nx * 32, Ls[db], (0 * 8 + wid), lane);
      stage_chunk(A, m0, K, nx * 32, Ls[db], (1 * 8 + wid), lane);
      stage_chunk(BT, n0, K, nx * 32, Ls[db] + 8192, wid, lane);
    }
  }

  if (MODE == 0) {
    const int Ncols = NTILES * 128;
#pragma unroll
    for (int mt = 0; mt < 4; ++mt)
#pragma unroll
      for (int i = 0; i < 4; ++i) {
        const int m = m0 + wr * 64 + mt * 16 + 4 * g + i;
        float* orow = fo + (size_t)m * Ncols + n0 + wc * 64 + c;
#pragma unroll
        for (int nt = 0; nt < 4; ++nt) orow[nt * 16] = acc[mt][nt][i];
      }
  } else {
    const int hh = ((bt & 15) << 1) | wc;  // head 0..31 within its third
    const int third = bt >> 4;             // 0=q 1=k 2=v
    if (third < 2) {
      _Float16* dst0 = (third == 0) ? outq : outk;
#pragma unroll
      for (int mt = 0; mt < 4; ++mt) {
        float ss[4];
#pragma unroll
        for (int i = 0; i < 4; ++i) {
          float s = 0.f;
#pragma unroll
          for (int nt = 0; nt < 4; ++nt) { const float v = acc[mt][nt][i]; s += v * v; }
          ss[i] = s;
        }
#pragma unroll
        for (int msk = 1; msk < 16; msk <<= 1)
#pragma unroll
          for (int i = 0; i < 4; ++i) ss[i] += __shfl_xor(ss[i], msk);
#pragma unroll
        for (int i = 0; i < 4; ++i) {
          const int m = m0 + wr * 64 + mt * 16 + 4 * g + i;
          const int b = m >> 11, pos = m & 2047;
          float inv = 1.0f / fmaxf(sqrtf(ss[i]), 1e-12f);
          if (third == 0) inv *= 0.1803368801f;  // 0.125 * log2(e) folded into q
          const float v0 = acc[mt][0][i] * inv, v1 = acc[mt][1][i] * inv;
          const float v2 = acc[mt][2][i] * inv, v3 = acc[mt][3][i] * inv;
          float sn, cs;
          __sincosf(freqs[pos * 32 + c], &sn, &cs);
          // fragment-order store: blk=pos>>5, frag=nt, lane=(c>>3)*32+(pos&31), elem=c&7
          _Float16* d = dst0 + ((size_t)((b << 5) | hh) * 64 + (pos >> 5)) * 2048 +
                        ((c >> 3) * 32 + (pos & 31)) * 8 + (c & 7);
          d[0]    = (_Float16)(v0 * cs - v1 * sn);
          d[512]  = (_Float16)(v1 * cs + v0 * sn);
          d[1024] = (_Float16)v2;
          d[1536] = (_Float16)v3;
        }
      }
    } else {
#pragma unroll
      for (int mt = 0; mt < 4; ++mt)
#pragma unroll
        for (int i = 0; i < 4; ++i) {
          const int m = m0 + wr * 64 + mt * 16 + 4 * g + i;
          const int b = m >> 11, pos = m & 2047;
          const int kvb = pos >> 5, sub2 = (pos >> 4) & 1, rem = pos & 15;
          const int vhi = (rem >> 2) & 1;
          const int vj = (rem & 3) + ((rem >> 3) << 2);
          const size_t hbase = ((size_t)((b << 5) | hh) * 64 + kvb) * 2048;
#pragma unroll
          for (int nt = 0; nt < 4; ++nt) {
            const int dta = nt >> 1;
            const int lfrag = vhi * 32 + (nt & 1) * 16 + c;
            outv[hbase + ((dta * 2 + sub2) * 64 + lfrag) * 8 + vj] = (_Float16)acc[mt][nt][i];
          }
        }
    }
  }
}

// ---------------- flash attention, swapped QK^T, fragment-order inputs ----------------
// NO kv-split: 1 wave = 32 q rows, FULL kv range (64 iters); grid 1024 = 4 blocks/CU.
// Eliminates pO round-trip (32MB w + 32MB r) + combine pass; normalize in-kernel and
// write attno in final [b][q][h*64] layout. XCD map: 8 heads/XCD -> 4MB K/V in L2.
// exp via bare v_exp_f32. All loads base + lane*16B (coalesced, direct L2).
__global__ __launch_bounds__(256) void attn_k(const _Float16* __restrict__ qf_,
                                              const _Float16* __restrict__ kf_,
                                              const _Float16* __restrict__ vf_,
                                              _Float16* __restrict__ attno) {
  const int tid = threadIdx.x;
  const int wid = tid >> 6;
  const int lane = tid & 63;
  const int l31 = tid & 31;
  const int hi = (tid >> 5) & 1;
  // XCD swizzle: 16 consecutive blocks (one bh) per XCD
  const int dd = blockIdx.x;
  const int xcd = dd & 7, j = dd >> 3;     // j in [0,128)
  const int bh = xcd * 8 + (j >> 4);       // [0,64)
  const int qg = j & 15;
  const int qb = (qg << 2) | wid;          // q-block 0..63
  const int q = qb * 32 + l31;

  const _Float16* qp = qf_ + ((size_t)bh * 64 + qb) * 2048 + lane * 8;
  h8 qfr[4];
#pragma unroll
  for (int dc = 0; dc < 4; ++dc) qfr[dc] = *(const h8*)(qp + dc * 512);

  const _Float16* kp = kf_ + (size_t)bh * 64 * 2048 + lane * 8;
  const _Float16* vp = vf_ + (size_t)bh * 64 * 2048 + lane * 8;

  f32x16 acc0, acc1;
#pragma unroll
  for (int e = 0; e < 16; ++e) { acc0[e] = 0.f; acc1[e] = 0.f; }
  float l0 = 0.f, l1 = 0.f, l2 = 0.f, l3 = 0.f;  // 4 independent lsum chains

  for (int it = 0; it < 64; ++it) {
    const _Float16* kb = kp + (size_t)it * 2048;
    const _Float16* vb = vp + (size_t)it * 2048;
    // all 8 loads issued up front (independent of QK/exp)
    h8 kf0 = *(const h8*)(kb);
    h8 kf1 = *(const h8*)(kb + 512);
    h8 kf2 = *(const h8*)(kb + 1024);
    h8 kf3 = *(const h8*)(kb + 1536);
    h8 v00 = *(const h8*)(vb);          // dta0 sub0
    h8 v01 = *(const h8*)(vb + 512);    // dta0 sub1
    h8 v10 = *(const h8*)(vb + 1024);   // dta1 sub0
    h8 v11 = *(const h8*)(vb + 1536);   // dta1 sub1

    f32x16 S;
#pragma unroll
    for (int e = 0; e < 16; ++e) S[e] = 0.f;
    __builtin_amdgcn_s_setprio(1);
    S = __builtin_amdgcn_mfma_f32_32x32x16_f16(kf0, qfr[0], S, 0, 0, 0);
    S = __builtin_amdgcn_mfma_f32_32x32x16_f16(kf1, qfr[1], S, 0, 0, 0);
    S = __builtin_amdgcn_mfma_f32_32x32x16_f16(kf2, qfr[2], S, 0, 0, 0);
    S = __builtin_amdgcn_mfma_f32_32x32x16_f16(kf3, qfr[3], S, 0, 0, 0);
    __builtin_amdgcn_s_setprio(0);

    // p = exp2(S) via single v_exp_f32 (scale pre-folded into q; |arg| bounded).
    float p[16];
#pragma unroll
    for (int e = 0; e < 16; ++e) p[e] = exp2_raw(S[e]);
    l0 += p[0]; l1 += p[1]; l2 += p[2]; l3 += p[3];
    l0 += p[4]; l1 += p[5]; l2 += p[6]; l3 += p[7];
    l0 += p[8]; l1 += p[9]; l2 += p[10]; l3 += p[11];
    l0 += p[12]; l1 += p[13]; l2 += p[14]; l3 += p[15];

    // packed fp16 conversion (RTZ): pb0 = p[0..7], pb1 = p[8..15]
    h2 c0 = cvt_pk(p[0], p[1]);
    h2 c1 = cvt_pk(p[2], p[3]);
    h2 c2 = cvt_pk(p[4], p[5]);
    h2 c3 = cvt_pk(p[6], p[7]);
    h2 c4 = cvt_pk(p[8], p[9]);
    h2 c5 = cvt_pk(p[10], p[11]);
    h2 c6 = cvt_pk(p[12], p[13]);
    h2 c7 = cvt_pk(p[14], p[15]);
    h4 x0 = __builtin_shufflevector(c0, c1, 0, 1, 2, 3);
    h4 x1 = __builtin_shufflevector(c2, c3, 0, 1, 2, 3);
    h4 x2 = __builtin_shufflevector(c4, c5, 0, 1, 2, 3);
    h4 x3 = __builtin_shufflevector(c6, c7, 0, 1, 2, 3);
    h8 pb0 = __builtin_shufflevector(x0, x1, 0, 1, 2, 3, 4, 5, 6, 7);
    h8 pb1 = __builtin_shufflevector(x2, x3, 0, 1, 2, 3, 4, 5, 6, 7);

    __builtin_amdgcn_s_setprio(1);
    acc0 = __builtin_amdgcn_mfma_f32_32x32x16_f16(v00, pb0, acc0, 0, 0, 0);
    acc0 = __builtin_amdgcn_mfma_f32_32x32x16_f16(v01, pb1, acc0, 0, 0, 0);
    acc1 = __builtin_amdgcn_mfma_f32_32x32x16_f16(v10, pb0, acc1, 0, 0, 0);
    acc1 = __builtin_amdgcn_mfma_f32_32x32x16_f16(v11, pb1, acc1, 0, 0, 0);
    __builtin_amdgcn_s_setprio(0);
  }

  float lsum = (l0 + l1) + (l2 + l3);
  lsum += __shfl_xor(lsum, 32);
  const float inv = 1.0f / lsum;

  const int b = bh >> 5, h = bh & 31;
  _Float16* orow = attno + ((size_t)b * 2048 + q) * 2048 + h * 64;
#pragma unroll
  for (int dta = 0; dta < 2; ++dta) {
#pragma unroll
    for (int blk = 0; blk < 4; ++blk) {
      h4 st;
#pragma unroll
      for (int e = 0; e < 4; ++e) {
        const float v = (dta == 0) ? acc0[blk * 4 + e] : acc1[blk * 4 + e];
        st[e] = (_Float16)(v * inv);
      }
      *(h4*)(orow + dta * 32 + blk * 8 + 4 * hi) = st;
    }
  }
}

extern "C" void kernel_launch(void* const* d_in, const int* in_sizes, int n_in,
                              void* d_out, int out_size, void* d_ws, size_t ws_size,
                              hipStream_t stream) {
  const float* x = (const float*)d_in[0];
  const float* wqkv = (const float*)d_in[1];
  const float* wout = (const float*)d_in[2];
  const float* freqs = (const float*)d_in[3];
  char* ws = (char*)d_ws;
  _Float16* xb    = (_Float16*)ws;                          // [0,16M)  gemm1 A input
  _Float16* attno = xb;                                     // [0,16M)  attn out (x dead)
  _Float16* wqkvT = (_Float16*)(ws + (size_t)(16 << 20));   // [16,40M) gemm1 B input
  _Float16* woutT = (_Float16*)(ws + (size_t)(40 << 20));   // [40,48M)
  _Float16* qn    = (_Float16*)(ws + (size_t)(48 << 20));   // [48,64M) q-frags
  _Float16* kn    = (_Float16*)(ws + (size_t)(64 << 20));   // [64,80M) k-frags
  _Float16* vT    = (_Float16*)(ws + (size_t)(80 << 20));   // [80,96M) v-frags
  float* out = (float*)d_out;

  convk<<<8192, 256, 0, stream>>>(x, xb, 2 * 2048 * 2048);
  transconv_k<<<(6144 / 64) * (2048 / 64), 256, 0, stream>>>(wqkv, wqkvT, 2048, 6144);
  transconv_k<<<(2048 / 64) * (2048 / 64), 256, 0, stream>>>(wout, woutT, 2048, 2048);
  // BM=256 BN=128, 512 threads: grid = (M/256) * (N/128)
  gemm_k<1><<<16 * 48, 512, 0, stream>>>(xb, wqkvT, 2048, 48, qn, kn, vT, freqs, nullptr);
  attn_k<<<1024, 256, 0, stream>>>(qn, kn, vT, attno);
  gemm_k<0><<<16 * 16, 512, 0, stream>>>(attno, woutT, 2048, 16, nullptr, nullptr, nullptr,
                                         nullptr, out);
}

// Round 15
// 292.097 us; speedup vs baseline: 1.0939x; 1.0123x over previous
//
#include <hip/hip_runtime.h>
#include <cstdint>

typedef _Float16 h2 __attribute__((ext_vector_type(2)));
typedef _Float16 h4 __attribute__((ext_vector_type(4)));
typedef _Float16 h8 __attribute__((ext_vector_type(8)));
typedef float f32x4 __attribute__((ext_vector_type(4)));
typedef float f32x16 __attribute__((ext_vector_type(16)));

__device__ __forceinline__ h2 cvt_pk(float a, float b) {
  return __builtin_bit_cast(h2, __builtin_amdgcn_cvt_pkrtz(a, b));
}

// single-instruction 2^x (exp2f without fast-math lowers to a multi-op ocml
// sequence; our args are bounded so the bare HW instruction is exact enough)
__device__ __forceinline__ float exp2_raw(float x) {
  float r;
  asm("v_exp_f32 %0, %1" : "=v"(r) : "v"(x));
  return r;
}

// ---------- async global->LDS, 16B per lane, wave-uniform LDS base ----------
__device__ __forceinline__ void g2l16(const void* g, void* l) {
  __builtin_amdgcn_global_load_lds(
      (__attribute__((address_space(1))) void*)(uintptr_t)(g),
      (__attribute__((address_space(3))) void*)(l), 16, 0, 0);
}

// ---------------- fp32 -> fp16 elementwise ----------------
__global__ __launch_bounds__(256) void convk(const float* __restrict__ in,
                                             _Float16* __restrict__ out, int n) {
  int i = (blockIdx.x * 256 + threadIdx.x) * 4;
  if (i + 3 < n) {
    const float4 v = *(const float4*)(in + i);
    h4 o;
    o[0] = (_Float16)v.x; o[1] = (_Float16)v.y; o[2] = (_Float16)v.z; o[3] = (_Float16)v.w;
    *(h4*)(out + i) = o;
  }
}

// ---------------- fp32 [R][C] -> fp16 [C][R] transpose-convert ----------------
__global__ __launch_bounds__(256) void transconv_k(const float* __restrict__ in,
                                                   _Float16* __restrict__ out,
                                                   int R, int C) {
  __shared__ float tile[64][65];
  const int tC = C >> 6;
  const int bc = blockIdx.x % tC, br = blockIdx.x / tC;
  const int r0 = br << 6, c0 = bc << 6;
  const int t = threadIdx.x;
  const int lr = t >> 4, lc = (t & 15) << 2;
#pragma unroll
  for (int p = 0; p < 4; ++p) {
    const float4 v = *(const float4*)(in + (size_t)(r0 + p * 16 + lr) * C + c0 + lc);
    tile[p * 16 + lr][lc + 0] = v.x;
    tile[p * 16 + lr][lc + 1] = v.y;
    tile[p * 16 + lr][lc + 2] = v.z;
    tile[p * 16 + lr][lc + 3] = v.w;
  }
  __syncthreads();
#pragma unroll
  for (int p = 0; p < 4; ++p) {
    const int oc = p * 16 + lr;  // out-row = in-col
    h4 v;
#pragma unroll
    for (int e = 0; e < 4; ++e) v[e] = (_Float16)tile[lc + e][oc];
    *(h4*)(out + (size_t)(c0 + oc) * R + r0 + lc) = v;
  }
}

// ---- staging: one 256rx32c (A, 2 chunks/thread) or 128rx32c (B, 1 chunk) tile ----
// LDS layout: row-major [row][32 fp16] (64B rows), XOR-swizzled: phys = log ^ ((row&6)<<3).
// global_load_lds writes LINEAR (wave-uniform dest + lane*16B); we pre-swizzle the
// per-lane GLOBAL source so linear LDS holds the swizzled layout (both-sides rule).
__device__ __forceinline__ void stage_chunk(const _Float16* X, int R0, int K, int kof,
                                            _Float16* ldsbase, int chunk, int lane) {
  const int b = chunk * 1024 + lane * 16;           // linear LDS byte offset
  const int l = b ^ (((b >> 6) & 6) << 3);          // logical byte (involution)
  const _Float16* src = X + (size_t)(R0 + (l >> 6)) * K + kof + ((l & 63) >> 1);
  g2l16(src, (char*)ldsbase + chunk * 1024);
}

// ---------------- GEMM: C[M][N] = A[M][K] * BT[N][K]^T  (fp16 in, fp32 acc) ----------------
// R12-measured best: BM=256 BN=128 BK=32, 512 threads (8 waves = 4wr x 2wc, 64x64/wave).
// Deep pipeline (T3/T4): 2-deep prefetch, counted s_waitcnt vmcnt(3), raw s_barrier,
// stage(t+2) after consume-barrier. T2 bank swizzle. T5 setprio.
// (Measured: 124 us gemm1, MfmaUtil 38.7%, VGPR 60, bank-conflict 0.)
// MODE 0: plain fp32 store to fo (N = NTILES*128)
// MODE 1: QKV epilogue: l2norm + rope; q/k/v written in attn FRAGMENT ORDER:
//   [bh][blk32][frag:4][lane:64][8 fp16]. Q additionally scaled by 0.125*log2(e).
template <int MODE>
__global__ __launch_bounds__(512) void gemm_k(
    const _Float16* __restrict__ A, const _Float16* __restrict__ BT,
    const int K, const int NTILES,
    _Float16* __restrict__ outq, _Float16* __restrict__ outk,
    _Float16* __restrict__ outv, const float* __restrict__ freqs,
    float* __restrict__ fo) {
  __shared__ __align__(16) _Float16 Ls[2][12288];  // [dbuf][A:8192 | B:4096] = 48KB
  const int tid = threadIdx.x;
  // XCD-chunked + 4bt x 2mb grouped ordering (gridDim.x % 8 == 0, MBC = cpx/NTILES)
  const int cpx = gridDim.x >> 3;
  const int xcd = blockIdx.x & 7, idx = blockIdx.x >> 3;
  const int MBC = cpx / NTILES;
  const int grp = idx >> 3, sub = idx & 7;
  const int bt = grp * 4 + (sub & 3);
  const int mb = xcd * MBC + (sub >> 2);
  const int m0 = mb * 256, n0 = bt * 128;
  const int wid = tid >> 6, lane = tid & 63;
  const int wr = wid >> 1, wc = wid & 1;  // 4 x 2 waves
  const int g = lane >> 4, c = lane & 15;

  f32x4 acc[4][4];
#pragma unroll
  for (int i = 0; i < 4; ++i)
#pragma unroll
    for (int j = 0; j < 4; ++j)
#pragma unroll
      for (int e = 0; e < 4; ++e) acc[i][j][e] = 0.f;

  const int sx = (c & 6) << 3;
  const int nk = K >> 5;

  // prologue: stage tiles 0,1 (3 g2l16/thread each; 6 outstanding)
#pragma unroll
  for (int t0 = 0; t0 < 2; ++t0) {
    stage_chunk(A, m0, K, t0 * 32, Ls[t0], (0 * 8 + wid), lane);
    stage_chunk(A, m0, K, t0 * 32, Ls[t0], (1 * 8 + wid), lane);
    stage_chunk(BT, n0, K, t0 * 32, Ls[t0] + 8192, wid, lane);
  }

  for (int kt = 0; kt < nk; ++kt) {
    if (kt < nk - 1) {
      asm volatile("s_waitcnt vmcnt(3)" ::: "memory");  // own stage(kt) done; kt+1 in flight
    } else {
      asm volatile("s_waitcnt vmcnt(0)" ::: "memory");  // last tile: drain
    }
    __builtin_amdgcn_s_barrier();  // all waves' stage(kt) complete -> buf ready
    const int db = kt & 1;
    const _Float16* Ab = Ls[db];
    const _Float16* Bb = Ls[db] + 8192;
    h8 af[4], bf[4];
#pragma unroll
    for (int t = 0; t < 4; ++t) {
      const int lg = (wr * 64 + t * 16 + c) * 64 + 16 * g;
      af[t] = *(const h8*)((const char*)Ab + (lg ^ sx));
    }
#pragma unroll
    for (int t = 0; t < 4; ++t) {
      const int lg = (wc * 64 + t * 16 + c) * 64 + 16 * g;
      bf[t] = *(const h8*)((const char*)Bb + (lg ^ sx));
    }
    __builtin_amdgcn_s_setprio(1);
#pragma unroll
    for (int i = 0; i < 4; ++i)
#pragma unroll
      for (int j = 0; j < 4; ++j)
        acc[i][j] = __builtin_amdgcn_mfma_f32_16x16x32_f16(af[i], bf[j], acc[i][j], 0, 0, 0);
    __builtin_amdgcn_s_setprio(0);
    __builtin_amdgcn_s_barrier();  // all waves consumed buf[db]
    const int nx = kt + 2;
    if (nx < nk) {  // overwrite buf[db]; overlaps compute of kt+1
      stage_chunk(A, m0, K, nx * 32, Ls[db], (0 * 8 + wid), lane);
      stage_chunk(A, m0, K, nx * 32, Ls[db], (1 * 8 + wid), lane);
      stage_chunk(BT, n0, K, nx * 32, Ls[db] + 8192, wid, lane);
    }
  }

  if (MODE == 0) {
    const int Ncols = NTILES * 128;
#pragma unroll
    for (int mt = 0; mt < 4; ++mt)
#pragma unroll
      for (int i = 0; i < 4; ++i) {
        const int m = m0 + wr * 64 + mt * 16 + 4 * g + i;
        float* orow = fo + (size_t)m * Ncols + n0 + wc * 64 + c;
#pragma unroll
        for (int nt = 0; nt < 4; ++nt) orow[nt * 16] = acc[mt][nt][i];
      }
  } else {
    const int hh = ((bt & 15) << 1) | wc;  // head 0..31 within its third
    const int third = bt >> 4;             // 0=q 1=k 2=v
    if (third < 2) {
      _Float16* dst0 = (third == 0) ? outq : outk;
#pragma unroll
      for (int mt = 0; mt < 4; ++mt) {
        float ss[4];
#pragma unroll
        for (int i = 0; i < 4; ++i) {
          float s = 0.f;
#pragma unroll
          for (int nt = 0; nt < 4; ++nt) { const float v = acc[mt][nt][i]; s += v * v; }
          ss[i] = s;
        }
#pragma unroll
        for (int msk = 1; msk < 16; msk <<= 1)
#pragma unroll
          for (int i = 0; i < 4; ++i) ss[i] += __shfl_xor(ss[i], msk);
#pragma unroll
        for (int i = 0; i < 4; ++i) {
          const int m = m0 + wr * 64 + mt * 16 + 4 * g + i;
          const int b = m >> 11, pos = m & 2047;
          float inv = 1.0f / fmaxf(sqrtf(ss[i]), 1e-12f);
          if (third == 0) inv *= 0.1803368801f;  // 0.125 * log2(e) folded into q
          const float v0 = acc[mt][0][i] * inv, v1 = acc[mt][1][i] * inv;
          const float v2 = acc[mt][2][i] * inv, v3 = acc[mt][3][i] * inv;
          float sn, cs;
          __sincosf(freqs[pos * 32 + c], &sn, &cs);
          // fragment-order store: blk=pos>>5, frag=nt, lane=(c>>3)*32+(pos&31), elem=c&7
          _Float16* d = dst0 + ((size_t)((b << 5) | hh) * 64 + (pos >> 5)) * 2048 +
                        ((c >> 3) * 32 + (pos & 31)) * 8 + (c & 7);
          d[0]    = (_Float16)(v0 * cs - v1 * sn);
          d[512]  = (_Float16)(v1 * cs + v0 * sn);
          d[1024] = (_Float16)v2;
          d[1536] = (_Float16)v3;
        }
      }
    } else {
#pragma unroll
      for (int mt = 0; mt < 4; ++mt)
#pragma unroll
        for (int i = 0; i < 4; ++i) {
          const int m = m0 + wr * 64 + mt * 16 + 4 * g + i;
          const int b = m >> 11, pos = m & 2047;
          const int kvb = pos >> 5, sub2 = (pos >> 4) & 1, rem = pos & 15;
          const int vhi = (rem >> 2) & 1;
          const int vj = (rem & 3) + ((rem >> 3) << 2);
          const size_t hbase = ((size_t)((b << 5) | hh) * 64 + kvb) * 2048;
#pragma unroll
          for (int nt = 0; nt < 4; ++nt) {
            const int dta = nt >> 1;
            const int lfrag = vhi * 32 + (nt & 1) * 16 + c;
            outv[hbase + ((dta * 2 + sub2) * 64 + lfrag) * 8 + vj] = (_Float16)acc[mt][nt][i];
          }
        }
    }
  }
}

// ---------------- flash attention, swapped QK^T, fragment-order inputs ----------------
// NO kv-split: 1 wave = 32 q rows, FULL kv range (64 iters); grid 1024.
// REGISTER double-buffer of K/V (named A/B sets, unroll-2): loads for tile t+1 are
// issued before computing tile t, so the L2 round-trip (~200-300 cyc) hides under the
// QK->exp->PV compute phase instead of stalling the first MFMA of every iteration.
// exp via bare v_exp_f32. Q pre-scaled by 0.125*log2e at the gemm1 epilogue.
__global__ __launch_bounds__(256) void attn_k(const _Float16* __restrict__ qf_,
                                              const _Float16* __restrict__ kf_,
                                              const _Float16* __restrict__ vf_,
                                              _Float16* __restrict__ attno) {
  const int tid = threadIdx.x;
  const int wid = tid >> 6;
  const int lane = tid & 63;
  const int l31 = tid & 31;
  const int hi = (tid >> 5) & 1;
  // XCD swizzle: 16 consecutive blocks (one bh) per XCD
  const int dd = blockIdx.x;
  const int xcd = dd & 7, j = dd >> 3;     // j in [0,128)
  const int bh = xcd * 8 + (j >> 4);       // [0,64)
  const int qg = j & 15;
  const int qb = (qg << 2) | wid;          // q-block 0..63
  const int q = qb * 32 + l31;

  const _Float16* qp = qf_ + ((size_t)bh * 64 + qb) * 2048 + lane * 8;
  h8 qfr[4];
#pragma unroll
  for (int dc = 0; dc < 4; ++dc) qfr[dc] = *(const h8*)(qp + dc * 512);

  const _Float16* kp = kf_ + (size_t)bh * 64 * 2048 + lane * 8;
  const _Float16* vp = vf_ + (size_t)bh * 64 * 2048 + lane * 8;

  f32x16 acc0, acc1;
#pragma unroll
  for (int e = 0; e < 16; ++e) { acc0[e] = 0.f; acc1[e] = 0.f; }
  float l0 = 0.f, l1 = 0.f, l2 = 0.f, l3 = 0.f;  // 4 independent lsum chains

  // one iteration's compute on a ready register set
  auto compute = [&](h8 k0, h8 k1, h8 k2, h8 k3, h8 w00, h8 w01, h8 w10, h8 w11) {
    f32x16 S;
#pragma unroll
    for (int e = 0; e < 16; ++e) S[e] = 0.f;
    __builtin_amdgcn_s_setprio(1);
    S = __builtin_amdgcn_mfma_f32_32x32x16_f16(k0, qfr[0], S, 0, 0, 0);
    S = __builtin_amdgcn_mfma_f32_32x32x16_f16(k1, qfr[1], S, 0, 0, 0);
    S = __builtin_amdgcn_mfma_f32_32x32x16_f16(k2, qfr[2], S, 0, 0, 0);
    S = __builtin_amdgcn_mfma_f32_32x32x16_f16(k3, qfr[3], S, 0, 0, 0);
    __builtin_amdgcn_s_setprio(0);
    float p[16];
#pragma unroll
    for (int e = 0; e < 16; ++e) p[e] = exp2_raw(S[e]);
    l0 += p[0]; l1 += p[1]; l2 += p[2]; l3 += p[3];
    l0 += p[4]; l1 += p[5]; l2 += p[6]; l3 += p[7];
    l0 += p[8]; l1 += p[9]; l2 += p[10]; l3 += p[11];
    l0 += p[12]; l1 += p[13]; l2 += p[14]; l3 += p[15];
    h2 c0 = cvt_pk(p[0], p[1]);
    h2 c1 = cvt_pk(p[2], p[3]);
    h2 c2 = cvt_pk(p[4], p[5]);
    h2 c3 = cvt_pk(p[6], p[7]);
    h2 c4 = cvt_pk(p[8], p[9]);
    h2 c5 = cvt_pk(p[10], p[11]);
    h2 c6 = cvt_pk(p[12], p[13]);
    h2 c7 = cvt_pk(p[14], p[15]);
    h4 x0 = __builtin_shufflevector(c0, c1, 0, 1, 2, 3);
    h4 x1 = __builtin_shufflevector(c2, c3, 0, 1, 2, 3);
    h4 x2 = __builtin_shufflevector(c4, c5, 0, 1, 2, 3);
    h4 x3 = __builtin_shufflevector(c6, c7, 0, 1, 2, 3);
    h8 pb0 = __builtin_shufflevector(x0, x1, 0, 1, 2, 3, 4, 5, 6, 7);
    h8 pb1 = __builtin_shufflevector(x2, x3, 0, 1, 2, 3, 4, 5, 6, 7);
    __builtin_amdgcn_s_setprio(1);
    acc0 = __builtin_amdgcn_mfma_f32_32x32x16_f16(w00, pb0, acc0, 0, 0, 0);
    acc0 = __builtin_amdgcn_mfma_f32_32x32x16_f16(w01, pb1, acc0, 0, 0, 0);
    acc1 = __builtin_amdgcn_mfma_f32_32x32x16_f16(w10, pb0, acc1, 0, 0, 0);
    acc1 = __builtin_amdgcn_mfma_f32_32x32x16_f16(w11, pb1, acc1, 0, 0, 0);
    __builtin_amdgcn_s_setprio(0);
  };

  // preload tile 0 -> set A
  h8 kA0 = *(const h8*)(kp);
  h8 kA1 = *(const h8*)(kp + 512);
  h8 kA2 = *(const h8*)(kp + 1024);
  h8 kA3 = *(const h8*)(kp + 1536);
  h8 vA0 = *(const h8*)(vp);
  h8 vA1 = *(const h8*)(vp + 512);
  h8 vA2 = *(const h8*)(vp + 1024);
  h8 vA3 = *(const h8*)(vp + 1536);

  for (int it = 0; it < 64; it += 2) {
    // issue loads(it+1) -> set B (consumed after compute-A)
    const _Float16* kb1 = kp + (size_t)(it + 1) * 2048;
    const _Float16* vb1 = vp + (size_t)(it + 1) * 2048;
    h8 kB0 = *(const h8*)(kb1);
    h8 kB1 = *(const h8*)(kb1 + 512);
    h8 kB2 = *(const h8*)(kb1 + 1024);
    h8 kB3 = *(const h8*)(kb1 + 1536);
    h8 vB0 = *(const h8*)(vb1);
    h8 vB1 = *(const h8*)(vb1 + 512);
    h8 vB2 = *(const h8*)(vb1 + 1024);
    h8 vB3 = *(const h8*)(vb1 + 1536);

    compute(kA0, kA1, kA2, kA3, vA0, vA1, vA2, vA3);

    if (it + 2 < 64) {
      // issue loads(it+2) -> set A (consumed after compute-B)
      const _Float16* kb2 = kp + (size_t)(it + 2) * 2048;
      const _Float16* vb2 = vp + (size_t)(it + 2) * 2048;
      kA0 = *(const h8*)(kb2);
      kA1 = *(const h8*)(kb2 + 512);
      kA2 = *(const h8*)(kb2 + 1024);
      kA3 = *(const h8*)(kb2 + 1536);
      vA0 = *(const h8*)(vb2);
      vA1 = *(const h8*)(vb2 + 512);
      vA2 = *(const h8*)(vb2 + 1024);
      vA3 = *(const h8*)(vb2 + 1536);
    }

    compute(kB0, kB1, kB2, kB3, vB0, vB1, vB2, vB3);
  }

  float lsum = (l0 + l1) + (l2 + l3);
  lsum += __shfl_xor(lsum, 32);
  const float inv = 1.0f / lsum;

  const int b = bh >> 5, h = bh & 31;
  _Float16* orow = attno + ((size_t)b * 2048 + q) * 2048 + h * 64;
#pragma unroll
  for (int dta = 0; dta < 2; ++dta) {
#pragma unroll
    for (int blk = 0; blk < 4; ++blk) {
      h4 st;
#pragma unroll
      for (int e = 0; e < 4; ++e) {
        const float v = (dta == 0) ? acc0[blk * 4 + e] : acc1[blk * 4 + e];
        st[e] = (_Float16)(v * inv);
      }
      *(h4*)(orow + dta * 32 + blk * 8 + 4 * hi) = st;
    }
  }
}

extern "C" void kernel_launch(void* const* d_in, const int* in_sizes, int n_in,
                              void* d_out, int out_size, void* d_ws, size_t ws_size,
                              hipStream_t stream) {
  const float* x = (const float*)d_in[0];
  const float* wqkv = (const float*)d_in[1];
  const float* wout = (const float*)d_in[2];
  const float* freqs = (const float*)d_in[3];
  char* ws = (char*)d_ws;
  _Float16* xb    = (_Float16*)ws;                          // [0,16M)  gemm1 A input
  _Float16* attno = xb;                                     // [0,16M)  attn out (x dead)
  _Float16* wqkvT = (_Float16*)(ws + (size_t)(16 << 20));   // [16,40M) gemm1 B input
  _Float16* woutT = (_Float16*)(ws + (size_t)(40 << 20));   // [40,48M)
  _Float16* qn    = (_Float16*)(ws + (size_t)(48 << 20));   // [48,64M) q-frags
  _Float16* kn    = (_Float16*)(ws + (size_t)(64 << 20));   // [64,80M) k-frags
  _Float16* vT    = (_Float16*)(ws + (size_t)(80 << 20));   // [80,96M) v-frags
  float* out = (float*)d_out;

  convk<<<8192, 256, 0, stream>>>(x, xb, 2 * 2048 * 2048);
  transconv_k<<<(6144 / 64) * (2048 / 64), 256, 0, stream>>>(wqkv, wqkvT, 2048, 6144);
  transconv_k<<<(2048 / 64) * (2048 / 64), 256, 0, stream>>>(wout, woutT, 2048, 2048);
  // BM=256 BN=128, 512 threads: grid = (M/256) * (N/128)
  gemm_k<1><<<16 * 48, 512, 0, stream>>>(xb, wqkvT, 2048, 48, qn, kn, vT, freqs, nullptr);
  attn_k<<<1024, 256, 0, stream>>>(qn, kn, vT, attno);
  gemm_k<0><<<16 * 16, 512, 0, stream>>>(attno, woutT, 2048, 16, nullptr, nullptr, nullptr,
                                         nullptr, out);
}